// Round 1
// baseline (2996.650 us; speedup 1.0000x reference)
//
#include <hip/hip_runtime.h>
#include <hip/hip_bf16.h>
#include <stdint.h>

#define AS1 __attribute__((address_space(1)))
#define AS3 __attribute__((address_space(3)))

typedef __bf16 bf16x8v __attribute__((ext_vector_type(8)));
typedef float f32x4 __attribute__((ext_vector_type(4)));

// ---------------- problem constants ----------------
// B=4, S=1024, H=2048, V=32000 ; BETA=0.1, TEMPERATURE=1.0
static constexpr int HDIM = 2048;
static constexpr int VDIM = 32000;
static constexpr int MROWS = 4096;   // B*S
static constexpr int SLEN = 1024;

// ---------------- workspace layout (bytes) ----------------
static constexpr size_t WH_BYTES = (size_t)VDIM * HDIM * 2;   // 131072000
static constexpr size_t XH_BYTES = (size_t)MROWS * HDIM * 2;  // 16777216
static constexpr size_t WH_OFF = 0;
static constexpr size_t WL_OFF = WH_OFF + WH_BYTES;
static constexpr size_t XH_OFF = WL_OFF + WH_BYTES;
static constexpr size_t XL_OFF = XH_OFF + XH_BYTES;
static constexpr size_t SM_OFF = XL_OFF + XH_BYTES;           // sum_exp main: 4096 f32
static constexpr size_t SR_OFF = SM_OFF + MROWS * 4;          // sum_exp ref
static constexpr size_t AM_OFF = SR_OFF + MROWS * 4;          // packed argmax: 4096 u64
static constexpr size_t LR_OFF = AM_OFF + MROWS * 8;          // per-row loss
static constexpr size_t WS_NEED = LR_OFF + MROWS * 4;

// ---------------- helpers ----------------
__device__ __forceinline__ void load16_to_lds(const void* g, void* l) {
    __builtin_amdgcn_global_load_lds((const AS1 uint32_t*)g, (AS3 uint32_t*)l, 16, 0, 0);
}

__device__ __forceinline__ unsigned short f2bf_bits(float v) {
    __hip_bfloat16 b = __float2bfloat16(v);
    unsigned short u;
    __builtin_memcpy(&u, &b, 2);
    return u;
}
__device__ __forceinline__ float bfbits2f(unsigned short u) {
    unsigned int x = ((unsigned int)u) << 16;
    float f;
    __builtin_memcpy(&f, &x, 4);
    return f;
}

// ---------------- fp32 -> bf16 hi/lo split ----------------
__global__ void split_kernel(const float* __restrict__ in, unsigned short* __restrict__ hi,
                             unsigned short* __restrict__ lo, long n4) {
    long idx = (long)blockIdx.x * blockDim.x + threadIdx.x;
    long stride = (long)gridDim.x * blockDim.x;
    const float4* in4 = (const float4*)in;
    for (; idx < n4; idx += stride) {
        float4 v = in4[idx];
        ushort4 h;
        h.x = f2bf_bits(v.x);
        h.y = f2bf_bits(v.y);
        h.z = f2bf_bits(v.z);
        h.w = f2bf_bits(v.w);
        ((ushort4*)hi)[idx] = h;
        if (lo != nullptr) {
            ushort4 l;
            l.x = f2bf_bits(v.x - bfbits2f(h.x));
            l.y = f2bf_bits(v.y - bfbits2f(h.y));
            l.z = f2bf_bits(v.z - bfbits2f(h.z));
            l.w = f2bf_bits(v.w - bfbits2f(h.w));
            ((ushort4*)lo)[idx] = l;
        }
    }
}

// ---------------- init accumulators ----------------
__global__ void init_kernel(float* __restrict__ sm, float* __restrict__ sr,
                            unsigned long long* __restrict__ am, int n) {
    int i = blockIdx.x * blockDim.x + threadIdx.x;
    if (i < n) {
        sm[i] = 0.0f;
        sr[i] = 0.0f;
        am[i] = 0ull;
    }
}

// ---------------- fused GEMM + row reduce ----------------
// C = A (M x K, row-major) * B^T (N x K, row-major), tile 128x128, BK=32.
// Never materializes C: reduces each tile into per-row sum_exp (atomicAdd) and
// packed (max,argmax) (atomicMax).
template <bool SPLIT, bool ARGMAX>
__global__ __launch_bounds__(256) void gemm_reduce(
    const unsigned short* __restrict__ Ahg, const unsigned short* __restrict__ Alg,
    const unsigned short* __restrict__ Bhg, const unsigned short* __restrict__ Blg,
    const float* __restrict__ bias, float* __restrict__ sum_exp,
    unsigned long long* __restrict__ amax, int K) {
    extern __shared__ char smem[];
    char* sAh = smem;            // 8192 B: 128 x 32 bf16
    char* sBh = smem + 8192;
    char* sAl = smem + 16384;    // only if SPLIT
    char* sBl = smem + 24576;

    const int tid = threadIdx.x;
    const int wave = tid >> 6, lane = tid & 63;
    const int row0 = blockIdx.x * 128, col0 = blockIdx.y * 128;
    const int wr = wave >> 1, wc = wave & 1;
    const int q = lane >> 4, m = lane & 15;

    f32x4 acc[4][4];
#pragma unroll
    for (int r = 0; r < 4; ++r)
#pragma unroll
        for (int c = 0; c < 4; ++c) acc[r][c] = (f32x4){0.f, 0.f, 0.f, 0.f};

    const unsigned short* gA = Ahg + (size_t)row0 * K;
    const unsigned short* gB = Bhg + (size_t)col0 * K;
    const unsigned short* gAl = SPLIT ? (Alg + (size_t)row0 * K) : nullptr;
    const unsigned short* gBl = SPLIT ? (Blg + (size_t)col0 * K) : nullptr;

    const int srow = lane >> 2;        // + 16*chunk
    const int scol = (lane & 3) * 8;   // bf16 elements

    for (int k0 = 0; k0 < K; k0 += 32) {
#pragma unroll
        for (int it = 0; it < 2; ++it) {
            const int chunk = wave + it * 4;           // 0..7, wave-uniform
            const int r = chunk * 16 + srow;
            const size_t goff = (size_t)r * K + (size_t)(k0 + scol);
            load16_to_lds(gA + goff, sAh + chunk * 1024);
            load16_to_lds(gB + goff, sBh + chunk * 1024);
            if (SPLIT) {
                load16_to_lds(gAl + goff, sAl + chunk * 1024);
                load16_to_lds(gBl + goff, sBl + chunk * 1024);
            }
        }
        __syncthreads();

        bf16x8v ah[4], bh[4], al[4], bl[4];
#pragma unroll
        for (int r = 0; r < 4; ++r) {
            const int off = (wr * 64 + r * 16 + m) * 64 + q * 16;  // bytes
            ah[r] = *(const bf16x8v*)(sAh + off);
            if (SPLIT) al[r] = *(const bf16x8v*)(sAl + off);
        }
#pragma unroll
        for (int c = 0; c < 4; ++c) {
            const int off = (wc * 64 + c * 16 + m) * 64 + q * 16;
            bh[c] = *(const bf16x8v*)(sBh + off);
            if (SPLIT) bl[c] = *(const bf16x8v*)(sBl + off);
        }
#pragma unroll
        for (int r = 0; r < 4; ++r)
#pragma unroll
            for (int c = 0; c < 4; ++c) {
                acc[r][c] = __builtin_amdgcn_mfma_f32_16x16x32_bf16(ah[r], bh[c], acc[r][c], 0, 0, 0);
                if (SPLIT) {
                    acc[r][c] = __builtin_amdgcn_mfma_f32_16x16x32_bf16(ah[r], bl[c], acc[r][c], 0, 0, 0);
                    acc[r][c] = __builtin_amdgcn_mfma_f32_16x16x32_bf16(al[r], bh[c], acc[r][c], 0, 0, 0);
                }
            }
        __syncthreads();
    }

    // ---- epilogue: per-row (within-tile) sum_exp / max / argmax ----
    float biasv[4];
#pragma unroll
    for (int c = 0; c < 4; ++c) biasv[c] = bias[col0 + wc * 64 + c * 16 + m];

#pragma unroll
    for (int r = 0; r < 4; ++r) {
#pragma unroll
        for (int reg = 0; reg < 4; ++reg) {
            float vsum = 0.0f, vmax = -1e30f;
            int varg = 0;
#pragma unroll
            for (int c = 0; c < 4; ++c) {
                const float v = acc[r][c][reg] + biasv[c];
                vsum += __expf(v);
                const int col = col0 + wc * 64 + c * 16 + m;
                if (v > vmax) { vmax = v; varg = col; }
            }
            // reduce across the 16 lanes sharing this row (low 4 lane bits)
#pragma unroll
            for (int off = 1; off < 16; off <<= 1) {
                vsum += __shfl_xor(vsum, off, 64);
                const float omax = __shfl_xor(vmax, off, 64);
                const int oarg = __shfl_xor(varg, off, 64);
                if (omax > vmax || (omax == vmax && oarg < varg)) { vmax = omax; varg = oarg; }
            }
            if (m == 0) {
                const int row = row0 + wr * 64 + r * 16 + q * 4 + reg;
                atomicAdd(&sum_exp[row], vsum);
                if (ARGMAX) {
                    unsigned u = __float_as_uint(vmax);
                    u = (u & 0x80000000u) ? ~u : (u | 0x80000000u);
                    const unsigned long long packed =
                        ((unsigned long long)u << 32) | (unsigned long long)(0xFFFFFFFFu - (unsigned)varg);
                    atomicMax(&amax[row], packed);
                }
            }
        }
    }
}

// ---------------- per-row finalize: exact fp32 dots at chosen col ----------------
__global__ void finalize_rows(const float* __restrict__ x, const float* __restrict__ w,
                              const float* __restrict__ bias, const float* __restrict__ rx,
                              const float* __restrict__ rw, const float* __restrict__ rbias,
                              const float* __restrict__ adv, const int* __restrict__ mask,
                              const float* __restrict__ sum_main, const float* __restrict__ sum_ref,
                              const unsigned long long* __restrict__ amax,
                              float* __restrict__ loss_rows) {
    const int wave = threadIdx.x >> 6, lane = threadIdx.x & 63;
    const int row = blockIdx.x * 4 + wave;
    if (row >= MROWS) return;

    const unsigned long long p = amax[row];
    const int c = (int)(0xFFFFFFFFu - (unsigned)(p & 0xFFFFFFFFull));

    const float4* xv = (const float4*)(x + (size_t)row * HDIM);
    const float4* wv = (const float4*)(w + (size_t)c * HDIM);
    const float4* rxv = (const float4*)(rx + (size_t)row * HDIM);
    const float4* rwv = (const float4*)(rw + (size_t)c * HDIM);

    float d1 = 0.0f, d2 = 0.0f;
#pragma unroll
    for (int i = 0; i < HDIM / 4 / 64; ++i) {
        const int idx = i * 64 + lane;
        const float4 a = xv[idx], b = wv[idx];
        d1 += a.x * b.x + a.y * b.y + a.z * b.z + a.w * b.w;
        const float4 e = rxv[idx], f = rwv[idx];
        d2 += e.x * f.x + e.y * f.y + e.z * f.z + e.w * f.w;
    }
#pragma unroll
    for (int off = 1; off < 64; off <<= 1) {
        d1 += __shfl_xor(d1, off, 64);
        d2 += __shfl_xor(d2, off, 64);
    }
    if (lane == 0) {
        const float chosen_lp = (d1 + bias[c]) - logf(sum_main[row]);
        const float ref_lp = (d2 + rbias[c]) - logf(sum_ref[row]);
        const float dd = ref_lp - chosen_lp;
        const float kl = expf(dd) - dd - 1.0f;
        const float a = adv[row / SLEN];
        // coef_1 = exp(chosen_lp - chosen_lp) = 1; coef_2 = clip(1,0.8,1.2) = 1
        const float pt = -a + 0.1f * kl;
        loss_rows[row] = pt * (float)mask[row];
    }
}

// ---------------- final scalar reduce ----------------
__global__ void reduce_final(const float* __restrict__ lr, const int* __restrict__ mask,
                             float* __restrict__ out, int n) {
    __shared__ float s1[256];
    __shared__ float s2[256];
    float a = 0.0f, b = 0.0f;
    for (int i = threadIdx.x; i < n; i += 256) {
        a += lr[i];
        b += (float)mask[i];
    }
    s1[threadIdx.x] = a;
    s2[threadIdx.x] = b;
    __syncthreads();
    for (int off = 128; off > 0; off >>= 1) {
        if ((int)threadIdx.x < off) {
            s1[threadIdx.x] += s1[threadIdx.x + off];
            s2[threadIdx.x] += s2[threadIdx.x + off];
        }
        __syncthreads();
    }
    if (threadIdx.x == 0) out[0] = s1[0] / fmaxf(s2[0], 1.0f);
}

extern "C" void kernel_launch(void* const* d_in, const int* in_sizes, int n_in,
                              void* d_out, int out_size, void* d_ws, size_t ws_size,
                              hipStream_t stream) {
    const float* x = (const float*)d_in[0];
    const float* w = (const float*)d_in[1];
    const float* bias = (const float*)d_in[2];
    const float* rx = (const float*)d_in[3];
    const float* rw = (const float*)d_in[4];
    const float* rbias = (const float*)d_in[5];
    const float* adv = (const float*)d_in[6];
    const int* mask = (const int*)d_in[7];

    if (ws_size < WS_NEED) return;  // fail loudly via validation rather than OOB

    char* ws = (char*)d_ws;
    unsigned short* wh = (unsigned short*)(ws + WH_OFF);
    unsigned short* wl = (unsigned short*)(ws + WL_OFF);
    unsigned short* xh = (unsigned short*)(ws + XH_OFF);
    unsigned short* xl = (unsigned short*)(ws + XL_OFF);
    float* sum_main = (float*)(ws + SM_OFF);
    float* sum_ref = (float*)(ws + SR_OFF);
    unsigned long long* amax = (unsigned long long*)(ws + AM_OFF);
    float* loss_rows = (float*)(ws + LR_OFF);

    const long wN4 = (long)VDIM * HDIM / 4;
    const long xN4 = (long)MROWS * HDIM / 4;

    // main model: hi+lo split conversion
    split_kernel<<<8192, 256, 0, stream>>>(w, wh, wl, wN4);
    split_kernel<<<2048, 256, 0, stream>>>(x, xh, xl, xN4);
    init_kernel<<<16, 256, 0, stream>>>(sum_main, sum_ref, amax, MROWS);

    // main GEMM: 3-term split (xh*wh + xh*wl + xl*wh), argmax + sum_exp
    gemm_reduce<true, true><<<dim3(MROWS / 128, VDIM / 128), 256, 32768, stream>>>(
        xh, xl, wh, wl, bias, sum_main, amax, HDIM);

    // ref model: hi-only, reuse buffers (main GEMM is done by stream order)
    split_kernel<<<8192, 256, 0, stream>>>(rw, wh, nullptr, wN4);
    split_kernel<<<2048, 256, 0, stream>>>(rx, xh, nullptr, xN4);
    gemm_reduce<false, false><<<dim3(MROWS / 128, VDIM / 128), 256, 16384, stream>>>(
        xh, nullptr, wh, nullptr, rbias, sum_ref, nullptr, HDIM);

    // exact fp32 dot at chosen col + per-row loss, then scalar reduce
    finalize_rows<<<MROWS / 4, 256, 0, stream>>>(x, w, bias, rx, rw, rbias, adv, mask,
                                                 sum_main, sum_ref, amax, loss_rows);
    reduce_final<<<1, 256, 0, stream>>>(loss_rows, mask, (float*)d_out, MROWS);
}

// Round 2
// 2092.863 us; speedup vs baseline: 1.4318x; 1.4318x over previous
//
#include <hip/hip_runtime.h>
#include <hip/hip_bf16.h>
#include <stdint.h>

#define AS1 __attribute__((address_space(1)))
#define AS3 __attribute__((address_space(3)))

typedef _Float16 f16x8 __attribute__((ext_vector_type(8)));
typedef float f32x4 __attribute__((ext_vector_type(4)));

// ---------------- problem constants ----------------
// B=4, S=1024, H=2048, V=32000 ; BETA=0.1, TEMPERATURE=1.0
static constexpr int HDIM = 2048;
static constexpr int VDIM = 32000;
static constexpr int MROWS = 4096;     // B*S
static constexpr int SLEN = 1024;
static constexpr int NCB = VDIM / 128; // 250 col-blocks per row

// ---------------- workspace layout (bytes) ----------------
static constexpr size_t WF_OFF = 0;                                 // fp16 weight (main, then ref)
static constexpr size_t WF_BYTES = (size_t)VDIM * HDIM * 2;         // 131072000
static constexpr size_t XF_OFF = WF_OFF + WF_BYTES;                 // fp16 x (main, then ref)
static constexpr size_t XF_BYTES = (size_t)MROWS * HDIM * 2;        // 16777216
static constexpr size_t SM_OFF = XF_OFF + XF_BYTES;                 // sum_exp main: 4096 f32
static constexpr size_t SR_OFF = SM_OFF + MROWS * 4;                // sum_exp ref
static constexpr size_t CAND_OFF = SR_OFF + MROWS * 4;              // per-(row,colblock) packed top1
static constexpr size_t CAND_BYTES = (size_t)MROWS * NCB * 8;       // 8192000
static constexpr size_t C2_OFF = CAND_OFF + CAND_BYTES;             // top-2 cols per row: int2
static constexpr size_t LR_OFF = C2_OFF + MROWS * 8;                // per-row loss
static constexpr size_t WS_NEED = LR_OFF + MROWS * 4;               // ~156.1 MB

// ---------------- helpers ----------------
__device__ __forceinline__ void load16_to_lds(const void* g, void* l) {
    __builtin_amdgcn_global_load_lds((const AS1 uint32_t*)g, (AS3 uint32_t*)l, 16, 0, 0);
}

// ---------------- fp32 -> fp16 convert ----------------
__global__ void conv_kernel(const float* __restrict__ in, _Float16* __restrict__ out, long n4) {
    long idx = (long)blockIdx.x * blockDim.x + threadIdx.x;
    long stride = (long)gridDim.x * blockDim.x;
    const float4* in4 = (const float4*)in;
    for (; idx < n4; idx += stride) {
        float4 v = in4[idx];
        union { _Float16 h[4]; ushort4 u; } o;
        o.h[0] = (_Float16)v.x;
        o.h[1] = (_Float16)v.y;
        o.h[2] = (_Float16)v.z;
        o.h[3] = (_Float16)v.w;
        ((ushort4*)out)[idx] = o.u;
    }
}

// ---------------- init accumulators ----------------
__global__ void init_kernel(float* __restrict__ sm, float* __restrict__ sr, int n) {
    int i = blockIdx.x * blockDim.x + threadIdx.x;
    if (i < n) {
        sm[i] = 0.0f;
        sr[i] = 0.0f;
    }
}

// ---------------- fused fp16 GEMM + row reduce ----------------
// C = A (M x K) * B^T (N x K), tile 128x128, BK=32, single fp16 pass.
// Reduces each tile into per-row sum_exp (atomicAdd). If ARGMAX, writes the
// block-local per-row top-1 (packed value|~col) into cand[row*NCB + by].
template <bool ARGMAX>
__global__ __launch_bounds__(256) void gemm_reduce(
    const _Float16* __restrict__ Ag, const _Float16* __restrict__ Bg,
    const float* __restrict__ bias, float* __restrict__ sum_exp,
    unsigned long long* __restrict__ cand, int K) {
    __shared__ char smem[16384];
    __shared__ unsigned long long candLds[128][2];
    char* sA = smem;          // 8192 B: 128 x 32 fp16
    char* sB = smem + 8192;

    const int tid = threadIdx.x;
    const int wave = tid >> 6, lane = tid & 63;
    const int row0 = blockIdx.x * 128, col0 = blockIdx.y * 128;
    const int wr = wave >> 1, wc = wave & 1;
    const int q = lane >> 4, m = lane & 15;

    f32x4 acc[4][4];
#pragma unroll
    for (int r = 0; r < 4; ++r)
#pragma unroll
        for (int c = 0; c < 4; ++c) acc[r][c] = (f32x4){0.f, 0.f, 0.f, 0.f};

    const _Float16* gA = Ag + (size_t)row0 * K;
    const _Float16* gB = Bg + (size_t)col0 * K;

    const int srow = lane >> 2;       // + 16*chunk
    const int scol = (lane & 3) * 8;  // fp16 elements

    for (int k0 = 0; k0 < K; k0 += 32) {
#pragma unroll
        for (int it = 0; it < 2; ++it) {
            const int chunk = wave + it * 4;  // 0..7, wave-uniform
            const int r = chunk * 16 + srow;
            const size_t goff = (size_t)r * K + (size_t)(k0 + scol);
            load16_to_lds(gA + goff, sA + chunk * 1024);
            load16_to_lds(gB + goff, sB + chunk * 1024);
        }
        __syncthreads();

        f16x8 ah[4], bh[4];
#pragma unroll
        for (int r = 0; r < 4; ++r)
            ah[r] = *(const f16x8*)(sA + (wr * 64 + r * 16 + m) * 64 + q * 16);
#pragma unroll
        for (int c = 0; c < 4; ++c)
            bh[c] = *(const f16x8*)(sB + (wc * 64 + c * 16 + m) * 64 + q * 16);
#pragma unroll
        for (int r = 0; r < 4; ++r)
#pragma unroll
            for (int c = 0; c < 4; ++c)
                acc[r][c] = __builtin_amdgcn_mfma_f32_16x16x32_f16(ah[r], bh[c], acc[r][c], 0, 0, 0);
        __syncthreads();
    }

    // ---- epilogue: per-row sum_exp + block-local top1 ----
    float biasv[4];
#pragma unroll
    for (int c = 0; c < 4; ++c) biasv[c] = bias[col0 + wc * 64 + c * 16 + m];

#pragma unroll
    for (int r = 0; r < 4; ++r) {
#pragma unroll
        for (int reg = 0; reg < 4; ++reg) {
            float vsum = 0.0f, vmax = -1e30f;
            int varg = 0;
#pragma unroll
            for (int c = 0; c < 4; ++c) {
                const float v = acc[r][c][reg] + biasv[c];
                vsum += __expf(v);
                const int col = col0 + wc * 64 + c * 16 + m;
                if (v > vmax) { vmax = v; varg = col; }
            }
            // reduce across the 16 lanes sharing this row (low 4 lane bits)
#pragma unroll
            for (int off = 1; off < 16; off <<= 1) {
                vsum += __shfl_xor(vsum, off, 64);
                const float omax = __shfl_xor(vmax, off, 64);
                const int oarg = __shfl_xor(varg, off, 64);
                if (omax > vmax || (omax == vmax && oarg < varg)) { vmax = omax; varg = oarg; }
            }
            if (m == 0) {
                const int lrow = wr * 64 + r * 16 + q * 4 + reg;
                atomicAdd(&sum_exp[row0 + lrow], vsum);
                if (ARGMAX) {
                    unsigned u = __float_as_uint(vmax);
                    u = (u & 0x80000000u) ? ~u : (u | 0x80000000u);
                    candLds[lrow][wc] =
                        ((unsigned long long)u << 32) | (unsigned long long)(0xFFFFFFFFu - (unsigned)varg);
                }
            }
        }
    }
    if (ARGMAX) {
        __syncthreads();
        if (tid < 128) {
            const unsigned long long a = candLds[tid][0], b = candLds[tid][1];
            cand[(size_t)(row0 + tid) * NCB + blockIdx.y] = (a > b) ? a : b;
        }
    }
}

// ---------------- global top-2 from the candidate table ----------------
__global__ void scan_top2(const unsigned long long* __restrict__ cand, int2* __restrict__ out) {
    const int row = blockIdx.x * 4 + (threadIdx.x >> 6);
    const int lane = threadIdx.x & 63;
    const unsigned long long* p = cand + (size_t)row * NCB;
    unsigned long long t1 = 0ull, t2 = 0ull;
    for (int i = lane; i < NCB; i += 64) {
        const unsigned long long v = p[i];
        if (v > t1) { t2 = t1; t1 = v; }
        else if (v > t2) t2 = v;
    }
#pragma unroll
    for (int off = 1; off < 64; off <<= 1) {
        const unsigned long long o1 = __shfl_xor(t1, off, 64);
        const unsigned long long o2 = __shfl_xor(t2, off, 64);
        if (o1 > t1) {
            t2 = (t1 > o2) ? t1 : o2;
            t1 = o1;
        } else {
            t2 = (t2 > o1) ? t2 : o1;
        }
    }
    if (lane == 0) {
        int2 c;
        c.x = (int)(0xFFFFFFFFu - (unsigned)(t1 & 0xFFFFFFFFull));
        c.y = (int)(0xFFFFFFFFu - (unsigned)(t2 & 0xFFFFFFFFull));
        out[row] = c;
    }
}

// ---------------- per-row finalize: exact fp32 dots at top-2 candidates ----------------
__global__ void finalize_rows(const float* __restrict__ x, const float* __restrict__ w,
                              const float* __restrict__ bias, const float* __restrict__ rx,
                              const float* __restrict__ rw, const float* __restrict__ rbias,
                              const float* __restrict__ adv, const int* __restrict__ mask,
                              const float* __restrict__ sum_main, const float* __restrict__ sum_ref,
                              const int2* __restrict__ cand2, float* __restrict__ loss_rows) {
    const int wave = threadIdx.x >> 6, lane = threadIdx.x & 63;
    const int row = blockIdx.x * 4 + wave;
    if (row >= MROWS) return;

    const int2 cc = cand2[row];
    const int c1 = cc.x, c2 = cc.y;

    const float4* xv = (const float4*)(x + (size_t)row * HDIM);
    const float4* rxv = (const float4*)(rx + (size_t)row * HDIM);
    const float4* w1 = (const float4*)(w + (size_t)c1 * HDIM);
    const float4* w2 = (const float4*)(w + (size_t)c2 * HDIM);
    const float4* r1 = (const float4*)(rw + (size_t)c1 * HDIM);
    const float4* r2 = (const float4*)(rw + (size_t)c2 * HDIM);

    float m1 = 0.f, m2 = 0.f, f1 = 0.f, f2 = 0.f;
#pragma unroll
    for (int i = 0; i < HDIM / 4 / 64; ++i) {
        const int idx = i * 64 + lane;
        const float4 a = xv[idx], e = rxv[idx];
        const float4 b1 = w1[idx], b2 = w2[idx];
        const float4 g1 = r1[idx], g2 = r2[idx];
        m1 += a.x * b1.x + a.y * b1.y + a.z * b1.z + a.w * b1.w;
        m2 += a.x * b2.x + a.y * b2.y + a.z * b2.z + a.w * b2.w;
        f1 += e.x * g1.x + e.y * g1.y + e.z * g1.z + e.w * g1.w;
        f2 += e.x * g2.x + e.y * g2.y + e.z * g2.z + e.w * g2.w;
    }
#pragma unroll
    for (int off = 1; off < 64; off <<= 1) {
        m1 += __shfl_xor(m1, off, 64);
        m2 += __shfl_xor(m2, off, 64);
        f1 += __shfl_xor(f1, off, 64);
        f2 += __shfl_xor(f2, off, 64);
    }
    if (lane == 0) {
        const float z1 = m1 + bias[c1], z2 = m2 + bias[c2];
        // exact fp32 argmax among candidates; tie -> smaller col (jnp.argmax rule)
        const bool pick1 = (z1 > z2) || (z1 == z2 && c1 < c2);
        const int c = pick1 ? c1 : c2;
        const float zc = pick1 ? z1 : z2;
        const float zr = (pick1 ? f1 : f2) + rbias[c];
        const float chosen_lp = zc - logf(sum_main[row]);
        const float ref_lp = zr - logf(sum_ref[row]);
        const float dd = ref_lp - chosen_lp;
        const float kl = expf(dd) - dd - 1.0f;
        const float a = adv[row / SLEN];
        // coef_1 = exp(chosen_lp - stop_grad(chosen_lp)) = 1; coef_2 = clip(1,.8,1.2) = 1
        const float pt = -a + 0.1f * kl;
        loss_rows[row] = pt * (float)mask[row];
    }
}

// ---------------- final scalar reduce ----------------
__global__ void reduce_final(const float* __restrict__ lr, const int* __restrict__ mask,
                             float* __restrict__ out, int n) {
    __shared__ float s1[256];
    __shared__ float s2[256];
    float a = 0.0f, b = 0.0f;
    for (int i = threadIdx.x; i < n; i += 256) {
        a += lr[i];
        b += (float)mask[i];
    }
    s1[threadIdx.x] = a;
    s2[threadIdx.x] = b;
    __syncthreads();
    for (int off = 128; off > 0; off >>= 1) {
        if ((int)threadIdx.x < off) {
            s1[threadIdx.x] += s1[threadIdx.x + off];
            s2[threadIdx.x] += s2[threadIdx.x + off];
        }
        __syncthreads();
    }
    if (threadIdx.x == 0) out[0] = s1[0] / fmaxf(s2[0], 1.0f);
}

extern "C" void kernel_launch(void* const* d_in, const int* in_sizes, int n_in,
                              void* d_out, int out_size, void* d_ws, size_t ws_size,
                              hipStream_t stream) {
    const float* x = (const float*)d_in[0];
    const float* w = (const float*)d_in[1];
    const float* bias = (const float*)d_in[2];
    const float* rx = (const float*)d_in[3];
    const float* rw = (const float*)d_in[4];
    const float* rbias = (const float*)d_in[5];
    const float* adv = (const float*)d_in[6];
    const int* mask = (const int*)d_in[7];

    if (ws_size < WS_NEED) return;

    char* ws = (char*)d_ws;
    _Float16* wf = (_Float16*)(ws + WF_OFF);
    _Float16* xf = (_Float16*)(ws + XF_OFF);
    float* sum_main = (float*)(ws + SM_OFF);
    float* sum_ref = (float*)(ws + SR_OFF);
    unsigned long long* cand = (unsigned long long*)(ws + CAND_OFF);
    int2* cand2 = (int2*)(ws + C2_OFF);
    float* loss_rows = (float*)(ws + LR_OFF);

    const long wN4 = (long)VDIM * HDIM / 4;
    const long xN4 = (long)MROWS * HDIM / 4;

    // main model fp16 conversion
    conv_kernel<<<8192, 256, 0, stream>>>(w, wf, wN4);
    conv_kernel<<<2048, 256, 0, stream>>>(x, xf, xN4);
    init_kernel<<<16, 256, 0, stream>>>(sum_main, sum_ref, MROWS);

    // main GEMM: single fp16 pass, sum_exp + candidate table
    gemm_reduce<true><<<dim3(MROWS / 128, NCB), 256, 0, stream>>>(
        xf, wf, bias, sum_main, cand, HDIM);

    // global fp16 top-2 per row
    scan_top2<<<MROWS / 4, 256, 0, stream>>>(cand, cand2);

    // ref model: reuse buffers (stream-ordered after main GEMM)
    conv_kernel<<<8192, 256, 0, stream>>>(rw, wf, wN4);
    conv_kernel<<<2048, 256, 0, stream>>>(rx, xf, xN4);
    gemm_reduce<false><<<dim3(MROWS / 128, NCB), 256, 0, stream>>>(
        xf, wf, rbias, sum_ref, nullptr, HDIM);

    // exact fp32 recheck of top-2 + per-row loss, then scalar reduce
    finalize_rows<<<MROWS / 4, 256, 0, stream>>>(x, w, bias, rx, rw, rbias, adv, mask,
                                                 sum_main, sum_ref, cand2, loss_rows);
    reduce_final<<<1, 256, 0, stream>>>(loss_rows, mask, (float*)d_out, MROWS);
}